// Round 7
// baseline (170.073 us; speedup 1.0000x reference)
//
#include <hip/hip_runtime.h>
#include <stdint.h>

// ---------------------------------------------------------------------------
// HeteNet round 9: feature-slice structure with BATCHED register-resident
// weight fragments. Weights are fetched from global wp exactly once per block
// (per-wave disjoint slices), issued as one batch per layer so the ~250cyc L2
// latency is exposed once per layer, not per MFMA chain.
// __launch_bounds__(256,2) frees the register allocator (round0-6 all ran at
// VGPR=64 and were load-latency serialized).
// Separate h1 / (xs|h2) LDS buffers -> only 4 block barriers.
// Carries verified algebra: gfrag bias-fold, one-hot L2 bias MFMA,
// transposed dataflow, unsorted xs staging + tokR indirection,
// <=3 fixup chains with per-lane select at L3.
// Kernels: prep -> main. ws holds wp (130 KiB).
// ---------------------------------------------------------------------------

typedef float v4f __attribute__((ext_vector_type(4)));
typedef short v8s __attribute__((ext_vector_type(8)));
typedef short v4s __attribute__((ext_vector_type(4)));
typedef float v4fa __attribute__((ext_vector_type(4), aligned(4)));

#define XS_STR 72      // xs row stride (shorts), 144 B
#define HS_STR 136     // h row stride (shorts), 272 B
#define WP2B 60        // frag-block index bases (blocks of 512 shorts)
#define WP3B 100
#define WPBB 110

#define SEL4(te, a0, a1, a2, a3) \
    ((te) < 2 ? ((te) == 0 ? (a0) : (a1)) : ((te) == 2 ? (a2) : (a3)))

#define MFMA __builtin_amdgcn_mfma_f32_16x16x32_bf16
#define WFRAG(blk) (*(const v8s*)(wp + (size_t)(blk) * 512 + lane * 8))

static __device__ __forceinline__ short f2bf(float f) {
    union { __bf16 b; short s; } u;
    u.b = (__bf16)f;
    return u.s;
}

static __device__ __forceinline__ v4s pack4r(const v4f a) {
    v4s r;
    r[0] = f2bf(fmaxf(a[0], 0.f));
    r[1] = f2bf(fmaxf(a[1], 0.f));
    r[2] = f2bf(fmaxf(a[2], 0.f));
    r[3] = f2bf(fmaxf(a[3], 0.f));
    return r;
}

// ---------------- weight prep: fragment-ready bf16 layout ----------------
__global__ void prep_kernel(const float* __restrict__ W1, const float* __restrict__ cW1,
                            const float* __restrict__ W2, const float* __restrict__ cW2,
                            const float* __restrict__ W3, const float* __restrict__ cW3,
                            const float* __restrict__ b1, const float* __restrict__ cb1,
                            const float* __restrict__ b2, const float* __restrict__ cb2,
                            short* __restrict__ wp) {
    int b = blockIdx.x, lane = threadIdx.x;
    int nl = lane & 15, quad = lane >> 4;
    short frag[8];
    if (b < 60) {
        int e = b / 12, rem = b % 12, ks = rem / 4, nt = rem % 4;
        int n = nt * 16 + nl;
#pragma unroll
        for (int j = 0; j < 8; j++) {
            int k = ks * 32 + quad * 8 + j;
            float v = 0.f;
            if (k < 68)       v = (e < 4) ? W1[(e * 68 + k) * 64 + n] : cW1[k * 64 + n];
            else if (k == 68) v = (e < 4) ? b1[e * 64 + n] : cb1[n];
            frag[j] = f2bf(v);
        }
    } else if (b < 100) {
        int u = b - 60, e = u / 8, ks = (u % 8) / 4, nt = u % 4;
        int n = nt * 16 + nl;
#pragma unroll
        for (int j = 0; j < 8; j++) {
            int k = ks * 32 + quad * 8 + j;
            frag[j] = f2bf((e < 4) ? W2[(e * 64 + k) * 64 + n] : cW2[k * 64 + n]);
        }
    } else if (b < 110) {
        int u = b - 100;
#pragma unroll
        for (int j = 0; j < 8; j++) {
            int ks = (u < 8) ? (u & 1) : (u - 8);
            int k  = ks * 32 + quad * 8 + j;
            float v;
            if (u < 8) { int ee = u >> 1; v = W3[(ee * 64 + k) * 16 + nl]; }
            else       { v = (nl == 0) ? cW3[k] : 0.f; }
            frag[j] = f2bf(v);
        }
    } else {
        int u = b - 110, net = u / 4, nt = u % 4;
        int n = nt * 16 + nl;
#pragma unroll
        for (int j = 0; j < 8; j++) {
            float v = 0.f;
            if (quad == 0 && j == 0) v = (net < 4) ? b2[net * 64 + n] : cb2[n];
            frag[j] = f2bf(v);
        }
    }
    v8s pk = { frag[0], frag[1], frag[2], frag[3], frag[4], frag[5], frag[6], frag[7] };
    *(v8s*)(wp + (size_t)b * 512 + lane * 8) = pk;
}

// ---------------- fused main kernel ----------------

__global__ __launch_bounds__(256, 2) void main_kernel(
    const float* __restrict__ obs, const int* __restrict__ hete,
    const float* __restrict__ gp, const short* __restrict__ wp,
    const float* __restrict__ b3, const float* __restrict__ cb3,
    float* __restrict__ out)
{
    // bufA: xs (stride 72, first 9216 shorts) during stage/L1; h2 (stride 136)
    // during L2/L3 (xs dead). bufB: h1 (stride 136). ~70 KB -> 2 blocks/CU.
    __shared__ __align__(16) short bufA[128 * HS_STR];
    __shared__ __align__(16) short bufB[128 * HS_STR];
    __shared__ int rowtok[128];
    __shared__ int wcnt[2][4];

    short* xs = bufA;
    short* h1 = bufB;
    short* h2 = bufA;

    const int tid = threadIdx.x, lane = tid & 63, w = tid >> 6;
    const int ml = lane & 15, quad = lane >> 4;
    const size_t base = (size_t)blockIdx.x * 128;

    // --- entry: issue obs loads + L1 weight-frag batch (both independent) ---
    const int ltk = tid >> 1, hh = tid & 1;
    const float4* src = (const float4*)(obs + (base + ltk) * 64 + hh * 32);
    float4 f[8];
#pragma unroll
    for (int t = 0; t < 8; t++) f[t] = src[t];

    // L1 frag batch: eW1[te][ks] (ks=2 is the gfrag/bias block), cW1f[3]
    v8s eW1[4][3], cW1f[3];
#pragma unroll
    for (int te = 0; te < 4; te++)
#pragma unroll
        for (int ks = 0; ks < 3; ks++)
            eW1[te][ks] = WFRAG((te * 3 + ks) * 4 + w);
#pragma unroll
    for (int ks = 0; ks < 3; ks++) cW1f[ks] = WFRAG((12 + ks) * 4 + w);

    const float* gpb = gp + (size_t)blockIdx.x * 4;
    float g0 = gpb[0], g1 = gpb[1], g2 = gpb[2], g3 = gpb[3];

    // --- 4-way stable partition of 128 tokens (waves 0,1) ---
    int e = 0, rank = 0;
    if (tid < 128) {
        e = hete[base + tid];
        unsigned long long ltm = (1ull << lane) - 1ull;
        unsigned long long m0 = __ballot(e == 0);
        unsigned long long m1 = __ballot(e == 1);
        unsigned long long m2 = __ballot(e == 2);
        unsigned long long m3 = __ballot(e == 3);
        if      (e == 0) rank = __popcll(m0 & ltm);
        else if (e == 1) rank = __popcll(m1 & ltm);
        else if (e == 2) rank = __popcll(m2 & ltm);
        else             rank = __popcll(m3 & ltm);
        if (lane == 0) {
            wcnt[w][0] = __popcll(m0); wcnt[w][1] = __popcll(m1);
            wcnt[w][2] = __popcll(m2); wcnt[w][3] = __popcll(m3);
        }
    }
    __syncthreads();   // bar_a

    const int c0 = wcnt[0][0] + wcnt[1][0];
    const int c1 = wcnt[0][1] + wcnt[1][1];
    const int c2 = wcnt[0][2] + wcnt[1][2];
    const int sgs1 = __builtin_amdgcn_readfirstlane(c0);
    const int sgs2 = __builtin_amdgcn_readfirstlane(c0 + c1);
    const int sgs3 = __builtin_amdgcn_readfirstlane(c0 + c1 + c2);
    const int SG[5] = { 0, sgs1, sgs2, sgs3, 128 };

    if (tid < 128) {
        int gsE  = SEL4(e, 0, sgs1, sgs2, sgs3);
        int woff = (w == 1) ? wcnt[0][e] : 0;
        rowtok[gsE + woff + rank] = tid;
    }

    // --- stage x UNSORTED (row = token id) ---
    {
        int rb = ltk * XS_STR + hh * 32;
#pragma unroll
        for (int t = 0; t < 4; t++) {
            float4 a0 = f[2 * t], a1 = f[2 * t + 1];
            v8s pk = { f2bf(a0.x), f2bf(a0.y), f2bf(a0.z), f2bf(a0.w),
                       f2bf(a1.x), f2bf(a1.y), f2bf(a1.z), f2bf(a1.w) };
            *(v8s*)&xs[rb + t * 8] = pk;
        }
    }
    __syncthreads();   // bar_b: rowtok + xs staged

    // per-tile sorted-row token ids (wave handles token col ml of each tile)
    int tokR[8];
#pragma unroll
    for (int mt = 0; mt < 8; mt++) tokR[mt] = rowtok[mt * 16 + ml];

    v8s gfrag = (v8s){0,0,0,0,0,0,0,0};
    v8s onef  = (v8s){0,0,0,0,0,0,0,0};
    if (quad == 0) {
        gfrag[0] = f2bf(g0); gfrag[1] = f2bf(g1);
        gfrag[2] = f2bf(g2); gfrag[3] = f2bf(g3);
        gfrag[4] = (short)0x3F80;
        onef[0]  = (short)0x3F80;
    }

    // =====================================================================
    // Layer 1: K=96 (2 LDS ks + gfrag init). All frags already in registers.
    // =====================================================================
    v4f accE[8], accC[8], fx[3];
    fx[0] = fx[1] = fx[2] = (v4f){0,0,0,0};

    {
        v4f tC = MFMA(cW1f[2], gfrag, (v4f){0,0,0,0}, 0, 0, 0);
#pragma unroll
        for (int mt = 0; mt < 8; mt++) accC[mt] = tC;
    }
#pragma unroll
    for (int te = 0; te < 4; te++) {
        int lo = SG[te], hi = SG[te + 1];
        if (lo < hi) {
            v4f tE = MFMA(eW1[te][2], gfrag, (v4f){0,0,0,0}, 0, 0, 0);
#pragma unroll
            for (int mt = 0; mt < 8; mt++)
                if (mt * 16 >= lo && mt * 16 < hi) accE[mt] = tE;
            if (te > 0 && (lo & 15)) fx[te - 1] = tE;
        }
    }

#pragma unroll
    for (int ks = 0; ks < 2; ks++) {
        v8s xr[8];
#pragma unroll
        for (int mt = 0; mt < 8; mt++)
            xr[mt] = *(const v8s*)&xs[tokR[mt] * XS_STR + ks * 32 + quad * 8];
#pragma unroll
        for (int mt = 0; mt < 8; mt++)
            accC[mt] = MFMA(cW1f[ks], xr[mt], accC[mt], 0, 0, 0);
#pragma unroll
        for (int te = 0; te < 4; te++) {
            int lo = SG[te], hi = SG[te + 1];
            if (lo < hi) {
#pragma unroll
                for (int mt = 0; mt < 8; mt++) {
                    if (mt * 16 >= lo && mt * 16 < hi)
                        accE[mt] = MFMA(eW1[te][ks], xr[mt], accE[mt], 0, 0, 0);
                    if (te > 0 && (lo & 15) && (lo >> 4) == mt)
                        fx[te - 1] = MFMA(eW1[te][ks], xr[mt], fx[te - 1], 0, 0, 0);
                }
            }
        }
    }

    // --- issue L2 frag batch now (hidden under h1 writes + bar_c) ---
    v8s eW2[4][2], cW2f[2], bE2[4], bC2;
#pragma unroll
    for (int te = 0; te < 4; te++) {
#pragma unroll
        for (int ks = 0; ks < 2; ks++)
            eW2[te][ks] = WFRAG(WP2B + (te * 2 + ks) * 4 + w);
        bE2[te] = WFRAG(WPBB + te * 4 + w);
    }
#pragma unroll
    for (int ks = 0; ks < 2; ks++) cW2f[ks] = WFRAG(WP2B + (8 + ks) * 4 + w);
    bC2 = WFRAG(WPBB + 16 + w);

    // h1 writes (bufB — no WAR with xs, no pre-write barrier)
    {
#pragma unroll
        for (int mt = 0; mt < 8; mt++) {
            int rb = (mt * 16 + ml) * HS_STR + w * 16 + quad * 4;
            *(v4s*)&h1[rb]      = pack4r(accE[mt]);
            *(v4s*)&h1[rb + 64] = pack4r(accC[mt]);
        }
#pragma unroll
        for (int bb = 0; bb < 3; bb++) {
            int lo = SG[bb + 1];
            if ((lo & 15) && lo < SG[bb + 2]) {
                int row  = (lo >> 4) * 16 + ml;
                int el   = (row >= sgs1) + (row >= sgs2) + (row >= sgs3);
                if (el == bb + 1)
                    *(v4s*)&h1[row * HS_STR + w * 16 + quad * 4] = pack4r(fx[bb]);
            }
        }
    }
    __syncthreads();   // bar_c: h1 visible

    // =====================================================================
    // Layer 2: K=64; bias via one-hot init. Writes h2 into bufA (xs dead).
    // =====================================================================
    v4f acc2E[8], acc2C[8], fx2[3];
    fx2[0] = fx2[1] = fx2[2] = (v4f){0,0,0,0};

    {
        v4f tC = MFMA(bC2, onef, (v4f){0,0,0,0}, 0, 0, 0);
#pragma unroll
        for (int mt = 0; mt < 8; mt++) acc2C[mt] = tC;
    }
#pragma unroll
    for (int te = 0; te < 4; te++) {
        int lo = SG[te], hi = SG[te + 1];
        if (lo < hi) {
            v4f tE = MFMA(bE2[te], onef, (v4f){0,0,0,0}, 0, 0, 0);
#pragma unroll
            for (int mt = 0; mt < 8; mt++)
                if (mt * 16 >= lo && mt * 16 < hi) acc2E[mt] = tE;
            if (te > 0 && (lo & 15)) fx2[te - 1] = tE;
        }
    }

#pragma unroll
    for (int ks = 0; ks < 2; ks++) {
        v8s hrE[8], hrC[8];
#pragma unroll
        for (int mt = 0; mt < 8; mt++) {
            int rb = (mt * 16 + ml) * HS_STR + ks * 32 + quad * 8;
            hrE[mt] = *(const v8s*)&h1[rb];
            hrC[mt] = *(const v8s*)&h1[rb + 64];
        }
#pragma unroll
        for (int mt = 0; mt < 8; mt++)
            acc2C[mt] = MFMA(cW2f[ks], hrC[mt], acc2C[mt], 0, 0, 0);
#pragma unroll
        for (int te = 0; te < 4; te++) {
            int lo = SG[te], hi = SG[te + 1];
            if (lo < hi) {
#pragma unroll
                for (int mt = 0; mt < 8; mt++) {
                    if (mt * 16 >= lo && mt * 16 < hi)
                        acc2E[mt] = MFMA(eW2[te][ks], hrE[mt], acc2E[mt], 0, 0, 0);
                    if (te > 0 && (lo & 15) && (lo >> 4) == mt)
                        fx2[te - 1] = MFMA(eW2[te][ks], hrE[mt], fx2[te - 1], 0, 0, 0);
                }
            }
        }
    }

    // --- issue L3 frag batch (hidden under h2 writes + bar_d) ---
    // tiles handled by this wave: mtA = w, mtB = w + 4
    const int teA3 = ((w * 16) >= sgs1) + ((w * 16) >= sgs2) + ((w * 16) >= sgs3);
    const int teB3 = (((w + 4) * 16) >= sgs1) + (((w + 4) * 16) >= sgs2) + (((w + 4) * 16) >= sgs3);
    v8s wA0 = WFRAG(WP3B + teA3 * 2 + 0), wA1 = WFRAG(WP3B + teA3 * 2 + 1);
    v8s wB0 = WFRAG(WP3B + teB3 * 2 + 0), wB1 = WFRAG(WP3B + teB3 * 2 + 1);
    v8s wV0 = WFRAG(WP3B + 8), wV1 = WFRAG(WP3B + 9);

    // h2 writes into bufA
    {
#pragma unroll
        for (int mt = 0; mt < 8; mt++) {
            int rb = (mt * 16 + ml) * HS_STR + w * 16 + quad * 4;
            *(v4s*)&h2[rb]      = pack4r(acc2E[mt]);
            *(v4s*)&h2[rb + 64] = pack4r(acc2C[mt]);
        }
#pragma unroll
        for (int bb = 0; bb < 3; bb++) {
            int lo = SG[bb + 1];
            if ((lo & 15) && lo < SG[bb + 2]) {
                int row  = (lo >> 4) * 16 + ml;
                int el   = (row >= sgs1) + (row >= sgs2) + (row >= sgs3);
                if (el == bb + 1)
                    *(v4s*)&h2[row * HS_STR + w * 16 + quad * 4] = pack4r(fx2[bb]);
            }
        }
    }
    __syncthreads();   // bar_d: h2 visible

    // =====================================================================
    // Layer 3: wave w owns tiles {w, w+4}; per-lane fixup select; one store.
    // =====================================================================
    const float cb3v = cb3[0];
#pragma unroll
    for (int j = 0; j < 2; j++) {
        const int mt  = w + 4 * j;
        const int row = mt * 16 + ml;
        const int el  = (row >= sgs1) + (row >= sgs2) + (row >= sgs3);
        const int tok = tokR[mt];

        int rb = row * HS_STR + quad * 8;
        v8s hE0 = *(const v8s*)&h2[rb];
        v8s hE1 = *(const v8s*)&h2[rb + 32];
        v8s hC0 = *(const v8s*)&h2[rb + 64];
        v8s hC1 = *(const v8s*)&h2[rb + 96];

        v8s w0 = j ? wB0 : wA0, w1 = j ? wB1 : wA1;
        v4f accL = MFMA(w0, hE0, (v4f){0,0,0,0}, 0, 0, 0);
        accL     = MFMA(w1, hE1, accL, 0, 0, 0);
        v4f accV = MFMA(wV0, hC0, (v4f){0,0,0,0}, 0, 0, 0);
        accV     = MFMA(wV1, hC1, accV, 0, 0, 0);

        // fixup: straddle tile recomputed with next expert, per-lane select
#pragma unroll
        for (int bb = 0; bb < 3; bb++) {
            int lo = SG[bb + 1];
            if ((lo & 15) && lo < SG[bb + 2] && (lo >> 4) == mt) {
                v4f v = MFMA(WFRAG(WP3B + (bb + 1) * 2 + 0), hE0, (v4f){0,0,0,0}, 0, 0, 0);
                v     = MFMA(WFRAG(WP3B + (bb + 1) * 2 + 1), hE1, v, 0, 0, 0);
#pragma unroll
                for (int rr = 0; rr < 4; rr++)
                    accL[rr] = (el == bb + 1) ? v[rr] : accL[rr];
            }
        }

        const v4fa b3v = *(const v4fa*)(b3 + el * 16 + quad * 4);
        float* o = out + (base + (size_t)tok) * 17;
        v4fa ov = { accL[0] + b3v[0], accL[1] + b3v[1],
                    accL[2] + b3v[2], accL[3] + b3v[3] };
        *(v4fa*)(o + quad * 4) = ov;
        if (quad == 0) o[16] = accV[0] + cb3v;
    }
}

// ---------------------------------------------------------------------------

extern "C" void kernel_launch(void* const* d_in, const int* in_sizes, int n_in,
                              void* d_out, int out_size, void* d_ws, size_t ws_size,
                              hipStream_t stream) {
    const float* obs = (const float*)d_in[0];
    const int*  hete = (const int*)d_in[1];
    const float* gp  = (const float*)d_in[2];
    const float* W1  = (const float*)d_in[3];
    const float* b1  = (const float*)d_in[4];
    const float* W2  = (const float*)d_in[5];
    const float* b2  = (const float*)d_in[6];
    const float* W3  = (const float*)d_in[7];
    const float* b3  = (const float*)d_in[8];
    const float* cW1 = (const float*)d_in[9];
    const float* cb1 = (const float*)d_in[10];
    const float* cW2 = (const float*)d_in[11];
    const float* cb2 = (const float*)d_in[12];
    const float* cW3 = (const float*)d_in[13];
    const float* cb3 = (const float*)d_in[14];
    float* out = (float*)d_out;

    short* wp = (short*)d_ws;   // 130 * 512 shorts = 133120 B

    prep_kernel<<<130,  64, 0, stream>>>(W1, cW1, W2, cW2, W3, cW3,
                                         b1, cb1, b2, cb2, wp);
    main_kernel<<<2048, 256, 0, stream>>>(obs, hete, gp, wp, b3, cb3, out);
}

// Round 9
// 156.682 us; speedup vs baseline: 1.0855x; 1.0855x over previous
//
#include <hip/hip_runtime.h>
#include <stdint.h>

// ---------------------------------------------------------------------------
// HeteNet round 11 (= audited round-10 design, resubmitted after infra
// failure; ws layout hardened: wp aliases dead cnt/bb, footprint now within
// 12 KB of the session-proven round-0 usage).
// Bucketed expert-pure blocks (round-0 bucketing) + fully REGISTER-RESIDENT
// 3-layer MLP via k-permuted weights: MFMA k-dim is positional, so permuting
// k identically in A and B preserves D. Layer-N D output (lane: token=l&15,
// feat=m*16+quad*4+rr) is consumed directly as layer-N+1 B with weights
// stored at k_in = 32ks + 16(j>>2) + 4quad + (j&3).
// -> h never touches LDS; zero inter-layer barriers; 1 block barrier total.
// Each wave: 2x16-token sub-tiles end-to-end (A-frags serve 32 tokens).
// Expert frag set (26 KB) staged once per block into LDS; critic frags from
// L2-hot wp.
// ws: hdr[32] | bucket[262656] | wp (aliases cnt[1024]|bb[1024] onward)
// ---------------------------------------------------------------------------

typedef float v4f __attribute__((ext_vector_type(4)));
typedef short v8s __attribute__((ext_vector_type(8)));
typedef float v4fa __attribute__((ext_vector_type(4), aligned(4)));

#define MFMA __builtin_amdgcn_mfma_f32_16x16x32_bf16

static __device__ __forceinline__ short f2bf(float f) {
    union { __bf16 b; short s; } u;
    u.b = (__bf16)f;   // native RNE convert
    return u.s;
}

// ---------------- bucketing (verbatim round-0, verified) ----------------

__global__ void count_kernel(const int* __restrict__ hete, int* __restrict__ cnt) {
    __shared__ int wc[4][4];
    int tid = threadIdx.x, lane = tid & 63, w = tid >> 6;
    int base = blockIdx.x * 1024;
    int lc[4] = {0, 0, 0, 0};
#pragma unroll
    for (int c = 0; c < 4; c++) {
        int e = hete[base + c * 256 + tid];
#pragma unroll
        for (int t = 0; t < 4; t++) {
            unsigned long long m = __ballot(e == t);
            if (lane == 0) lc[t] += __popcll(m);
        }
    }
    if (lane == 0)
#pragma unroll
        for (int t = 0; t < 4; t++) wc[w][t] = lc[t];
    __syncthreads();
    if (tid < 4)
        cnt[blockIdx.x * 4 + tid] = wc[0][tid] + wc[1][tid] + wc[2][tid] + wc[3][tid];
}

__global__ void prefix_kernel(const int* __restrict__ cnt, int* __restrict__ hdr,
                              int* __restrict__ bb, int* __restrict__ bucket) {
    __shared__ int s[4][256];
    __shared__ int sa[5], sC[4];
    int tid = threadIdx.x;
    int c0[4];
#pragma unroll
    for (int t = 0; t < 4; t++) { c0[t] = cnt[tid * 4 + t]; s[t][tid] = c0[t]; }
    __syncthreads();
    for (int off = 1; off < 256; off <<= 1) {
        int v[4];
#pragma unroll
        for (int t = 0; t < 4; t++) v[t] = (tid >= off) ? s[t][tid - off] : 0;
        __syncthreads();
#pragma unroll
        for (int t = 0; t < 4; t++) s[t][tid] += v[t];
        __syncthreads();
    }
    if (tid == 0) {
        int a = 0, ts = 0;
        for (int e = 0; e < 4; e++) {
            int c = s[e][255];
            sC[e] = c;
            sa[e] = a;
            hdr[8 + e]  = a;
            hdr[13 + e] = ts;
            int tiles = (c + 127) >> 7;
            a  += tiles << 7;
            ts += tiles;
        }
        sa[4]   = a;
        hdr[12] = a;
        hdr[17] = ts;
    }
    __syncthreads();
#pragma unroll
    for (int t = 0; t < 4; t++) bb[tid * 4 + t] = sa[t] + s[t][tid] - c0[t];
    for (int e = 0; e < 4; e++) {
        int start = sa[e] + sC[e], end = sa[e + 1];
        for (int i = start + tid; i < end; i += 256) bucket[i] = -1;
    }
}

__global__ void scatter_kernel(const int* __restrict__ hete, const int* __restrict__ bb,
                               int* __restrict__ bucket) {
    __shared__ int cur[4];
    int tid = threadIdx.x, lane = tid & 63;
    if (tid < 4) cur[tid] = bb[blockIdx.x * 4 + tid];
    __syncthreads();
    unsigned long long lt = (1ull << lane) - 1ull;
#pragma unroll
    for (int c = 0; c < 4; c++) {
        int i = blockIdx.x * 1024 + c * 256 + tid;
        int e = hete[i];
        int slot = 0;
#pragma unroll
        for (int t = 0; t < 4; t++) {
            unsigned long long m = __ballot(e == t);
            int n = __popcll(m);
            int wb = 0;
            if (lane == 0 && n) wb = atomicAdd(&cur[t], n);
            wb = __shfl(wb, 0);
            if (e == t) slot = wb + __popcll(m & lt);
        }
        bucket[slot] = i;
    }
}

// ---------------- weight prep ----------------
// Frag-block = 512 shorts: lane l holds out-feat nl=l&15, k-slot (quad,j).
// L1 (blocks 0..59): natural k = ks*32+quad*8+j; k==68 carries bias (gfrag 1.0).
// L2 (60..99) and L3 (100..109): PERMUTED k_in = 32ks+16(j>>2)+4quad+(j&3)
//   to match the D-register layout of the previous layer's accumulator.
// Bias frags (110..129): value only at (quad==0, j==0) — paired with onef.
__global__ void prep_kernel(const float* __restrict__ W1, const float* __restrict__ cW1,
                            const float* __restrict__ W2, const float* __restrict__ cW2,
                            const float* __restrict__ W3, const float* __restrict__ cW3,
                            const float* __restrict__ b1, const float* __restrict__ cb1,
                            const float* __restrict__ b2, const float* __restrict__ cb2,
                            short* __restrict__ wp) {
    int b = blockIdx.x, lane = threadIdx.x;
    int nl = lane & 15, quad = lane >> 4;
    short frag[8];
    if (b < 60) {
        int e = b / 12, rem = b % 12, ks = rem / 4, nt = rem % 4;
        int n = nt * 16 + nl;
#pragma unroll
        for (int j = 0; j < 8; j++) {
            int k = ks * 32 + quad * 8 + j;
            float v = 0.f;
            if (k < 68)       v = (e < 4) ? W1[(e * 68 + k) * 64 + n] : cW1[k * 64 + n];
            else if (k == 68) v = (e < 4) ? b1[e * 64 + n] : cb1[n];
            frag[j] = f2bf(v);
        }
    } else if (b < 100) {
        // L2 permuted: net = u/8 (4 = critic), ks = (u&7)>>2, m = u&3
        int u = b - 60, net = u / 8, ks = (u & 7) >> 2, m = u & 3;
        int n = m * 16 + nl;
#pragma unroll
        for (int j = 0; j < 8; j++) {
            int kin = ks * 32 + 16 * (j >> 2) + quad * 4 + (j & 3);
            frag[j] = f2bf((net < 4) ? W2[(net * 64 + kin) * 64 + n] : cW2[kin * 64 + n]);
        }
    } else if (b < 110) {
        // L3 permuted: u<8: net=u>>1, ks=u&1 ; u>=8: critic value, ks=u-8
        int u = b - 100;
#pragma unroll
        for (int j = 0; j < 8; j++) {
            int ks = (u < 8) ? (u & 1) : (u - 8);
            int kin = ks * 32 + 16 * (j >> 2) + quad * 4 + (j & 3);
            float v;
            if (u < 8) { int net = u >> 1; v = W3[(net * 64 + kin) * 16 + nl]; }
            else       { v = (nl == 0) ? cW3[kin] : 0.f; }
            frag[j] = f2bf(v);
        }
    } else {
        int u = b - 110, net = u / 4, m = u % 4;
        int n = m * 16 + nl;
#pragma unroll
        for (int j = 0; j < 8; j++) {
            float v = 0.f;
            if (quad == 0 && j == 0) v = (net < 4) ? b2[net * 64 + n] : cb2[n];
            frag[j] = f2bf(v);
        }
    }
    v8s pk = { frag[0], frag[1], frag[2], frag[3], frag[4], frag[5], frag[6], frag[7] };
    *(v8s*)(wp + (size_t)b * 512 + lane * 8) = pk;
}

// ---------------- main fused kernel ----------------

__global__ __launch_bounds__(256, 4) void main_kernel(
    const float* __restrict__ obs, const float* __restrict__ gp,
    const int* __restrict__ bucket, const int* __restrict__ hdr,
    const short* __restrict__ wp,
    const float* __restrict__ b3, const float* __restrict__ cb3,
    float* __restrict__ out)
{
    // LDS: only the block's expert frag set (26 frag-blocks = 26624 B).
    // Local order: [0..11] L1 (ks*4+m, ks=0..2), [12..19] L2 (ks*4+m),
    //              [20..23] L2 bias (m), [24..25] L3 (ks).
    __shared__ __align__(16) short lwp[26 * 512];

    const int b = blockIdx.x;
    const int total = hdr[17];
    if (b >= total) return;
    int e = 3;
    if      (b < hdr[14]) e = 0;
    else if (b < hdr[15]) e = 1;
    else if (b < hdr[16]) e = 2;
    const int slot0 = hdr[8 + e] + (b - hdr[13 + e]) * 128;

    const int tid = threadIdx.x, lane = tid & 63, w = tid >> 6;
    const int nl = lane & 15, quad = lane >> 4;

    // --- stage expert frags to LDS (linear uint4 copy) ---
    {
        const uint4* wp4 = (const uint4*)wp;
        uint4* l4 = (uint4*)lwp;
        for (int i = tid; i < 26 * 64; i += 256) {
            int lb = i >> 6, off = i & 63;
            int g = (lb < 12) ? (e * 12 + lb)
                  : (lb < 20) ? (60 + e * 8 + lb - 12)
                  : (lb < 24) ? (110 + e * 4 + lb - 20)
                              : (100 + e * 2 + lb - 24);
            l4[i] = wp4[(size_t)g * 64 + off];
        }
    }

    // --- tokens + x B-frags (independent of LDS; issued before barrier) ---
    const int tk0 = bucket[slot0 + w * 32 + nl];
    const int tk1 = bucket[slot0 + w * 32 + 16 + nl];

    v8s xb0[2], xb1[2], gf0, gf1;
    {
        v8s z = { 0, 0, 0, 0, 0, 0, 0, 0 };
        xb0[0] = xb0[1] = xb1[0] = xb1[1] = gf0 = gf1 = z;
        if (tk0 >= 0) {
#pragma unroll
            for (int ks = 0; ks < 2; ks++) {
                const float4* s = (const float4*)(obs + (size_t)tk0 * 64 + ks * 32 + quad * 8);
                float4 a = s[0], c = s[1];
                xb0[ks] = (v8s){ f2bf(a.x), f2bf(a.y), f2bf(a.z), f2bf(a.w),
                                 f2bf(c.x), f2bf(c.y), f2bf(c.z), f2bf(c.w) };
            }
            if (quad == 0) {
                float4 g = *(const float4*)(gp + (size_t)(tk0 >> 7) * 4);
                gf0 = (v8s){ f2bf(g.x), f2bf(g.y), f2bf(g.z), f2bf(g.w),
                             (short)0x3F80, 0, 0, 0 };
            }
        }
        if (tk1 >= 0) {
#pragma unroll
            for (int ks = 0; ks < 2; ks++) {
                const float4* s = (const float4*)(obs + (size_t)tk1 * 64 + ks * 32 + quad * 8);
                float4 a = s[0], c = s[1];
                xb1[ks] = (v8s){ f2bf(a.x), f2bf(a.y), f2bf(a.z), f2bf(a.w),
                                 f2bf(c.x), f2bf(c.y), f2bf(c.z), f2bf(c.w) };
            }
            if (quad == 0) {
                float4 g = *(const float4*)(gp + (size_t)(tk1 >> 7) * 4);
                gf1 = (v8s){ f2bf(g.x), f2bf(g.y), f2bf(g.z), f2bf(g.w),
                             (short)0x3F80, 0, 0, 0 };
            }
        }
    }
    v8s onef = (v8s){ 0, 0, 0, 0, 0, 0, 0, 0 };
    if (quad == 0) onef[0] = (short)0x3F80;

    __syncthreads();   // expert frags staged. ONLY block barrier.

#define LFRAG(lb) (*(const v8s*)&lwp[(size_t)(lb) * 512 + lane * 8])
#define WFRAG(g)  (*(const v8s*)(wp + (size_t)(g) * 512 + lane * 8))

    // =====================================================================
    // EXPERT net: L1 -> (pack) -> L2 -> (pack) -> L3, all in registers.
    // acc D layout: token = l&15, feature = m*16 + quad*4 + rr.
    // pack: B-frag(ks)[j] = relu(acc[2ks + (j>>2)][j&3]) — matches pi.
    // =====================================================================
    {
        v4f aA[4], aB[4];
#pragma unroll
        for (int m = 0; m < 4; m++) {
            v8s wg = LFRAG(8 + m);   // L1 ks=2 block: gp cols + bias@k68
            aA[m] = MFMA(wg, gf0, (v4f){0, 0, 0, 0}, 0, 0, 0);
            aB[m] = MFMA(wg, gf1, (v4f){0, 0, 0, 0}, 0, 0, 0);
        }
#pragma unroll
        for (int ks = 0; ks < 2; ks++)
#pragma unroll
            for (int m = 0; m < 4; m++) {
                v8s wk = LFRAG(ks * 4 + m);
                aA[m] = MFMA(wk, xb0[ks], aA[m], 0, 0, 0);
                aB[m] = MFMA(wk, xb1[ks], aB[m], 0, 0, 0);
            }

        v8s pA[2], pB[2];
#pragma unroll
        for (int ks = 0; ks < 2; ks++) {
            v8s ta, tb;
#pragma unroll
            for (int j = 0; j < 8; j++) {
                ta[j] = f2bf(fmaxf(aA[2 * ks + (j >> 2)][j & 3], 0.f));
                tb[j] = f2bf(fmaxf(aB[2 * ks + (j >> 2)][j & 3], 0.f));
            }
            pA[ks] = ta; pB[ks] = tb;
        }

        v4f cA[4], cB[4];
#pragma unroll
        for (int m = 0; m < 4; m++) {
            v8s bf = LFRAG(20 + m);
            cA[m] = MFMA(bf, onef, (v4f){0, 0, 0, 0}, 0, 0, 0);
            cB[m] = MFMA(bf, onef, (v4f){0, 0, 0, 0}, 0, 0, 0);
        }
#pragma unroll
        for (int ks = 0; ks < 2; ks++)
#pragma unroll
            for (int m = 0; m < 4; m++) {
                v8s wk = LFRAG(12 + ks * 4 + m);
                cA[m] = MFMA(wk, pA[ks], cA[m], 0, 0, 0);
                cB[m] = MFMA(wk, pB[ks], cB[m], 0, 0, 0);
            }

        v8s qA[2], qB[2];
#pragma unroll
        for (int ks = 0; ks < 2; ks++) {
            v8s ta, tb;
#pragma unroll
            for (int j = 0; j < 8; j++) {
                ta[j] = f2bf(fmaxf(cA[2 * ks + (j >> 2)][j & 3], 0.f));
                tb[j] = f2bf(fmaxf(cB[2 * ks + (j >> 2)][j & 3], 0.f));
            }
            qA[ks] = ta; qB[ks] = tb;
        }

        v4f LA = (v4f){0, 0, 0, 0}, LB = (v4f){0, 0, 0, 0};
#pragma unroll
        for (int ks = 0; ks < 2; ks++) {
            v8s wk = LFRAG(24 + ks);
            LA = MFMA(wk, qA[ks], LA, 0, 0, 0);
            LB = MFMA(wk, qB[ks], LB, 0, 0, 0);
        }

        // logits store: lane holds logits quad*4..+3 of its token
        v4fa b3v = *(const v4fa*)(b3 + e * 16 + quad * 4);
        if (tk0 >= 0) {
            float* o = out + (size_t)tk0 * 17;
            v4fa ov = { LA[0] + b3v[0], LA[1] + b3v[1], LA[2] + b3v[2], LA[3] + b3v[3] };
            *(v4fa*)(o + quad * 4) = ov;
        }
        if (tk1 >= 0) {
            float* o = out + (size_t)tk1 * 17;
            v4fa ov = { LB[0] + b3v[0], LB[1] + b3v[1], LB[2] + b3v[2], LB[3] + b3v[3] };
            *(v4fa*)(o + quad * 4) = ov;
        }
    }

    // =====================================================================
    // CRITIC net: same flow, frags from L2-hot global wp.
    // L1: 48+ks*4+m (ks=0,1), g-block 56+m. L2: 92+ks*4+m, bias 126+m.
    // L3 value row: 108+ks (nonzero only at out-row 0).
    // =====================================================================
    {
        v4f aA[4], aB[4];
#pragma unroll
        for (int m = 0; m < 4; m++) {
            v8s wg = WFRAG(56 + m);
            aA[m] = MFMA(wg, gf0, (v4f){0, 0, 0, 0}, 0, 0, 0);
            aB[m] = MFMA(wg, gf1, (v4f){0, 0, 0, 0}, 0, 0, 0);
        }
#pragma unroll
        for (int ks = 0; ks < 2; ks++)
#pragma unroll
            for (int m = 0; m < 4; m++) {
                v8s wk = WFRAG(48 + ks * 4 + m);
                aA[m] = MFMA(wk, xb0[ks], aA[m], 0, 0, 0);
                aB[m] = MFMA(wk, xb1[ks], aB[m], 0, 0, 0);
            }

        v8s pA[2], pB[2];
#pragma unroll
        for (int ks = 0; ks < 2; ks++) {
            v8s ta, tb;
#pragma unroll
            for (int j = 0; j < 8; j++) {
                ta[j] = f2bf(fmaxf(aA[2 * ks + (j >> 2)][j & 3], 0.f));
                tb[j] = f2bf(fmaxf(aB[2 * ks + (j >> 2)][j & 3], 0.f));
            }
            pA[ks] = ta; pB[ks] = tb;
        }

        v4f cA[4], cB[4];
#pragma unroll
        for (int m = 0; m < 4; m++) {
            v8s bf = WFRAG(126 + m);
            cA[m] = MFMA(bf, onef, (v4f){0, 0, 0, 0}, 0, 0, 0);
            cB[m] = MFMA(bf, onef, (v4f){0, 0, 0, 0}, 0, 0, 0);
        }
#pragma unroll
        for (int ks = 0; ks < 2; ks++)
#pragma unroll
            for (int m = 0; m < 4; m++) {
                v8s wk = WFRAG(92 + ks * 4 + m);
                cA[m] = MFMA(wk, pA[ks], cA[m], 0, 0, 0);
                cB[m] = MFMA(wk, pB[ks], cB[m], 0, 0, 0);
            }

        v8s qA[2], qB[2];
#pragma unroll
        for (int ks = 0; ks < 2; ks++) {
            v8s ta, tb;
#pragma unroll
            for (int j = 0; j < 8; j++) {
                ta[j] = f2bf(fmaxf(cA[2 * ks + (j >> 2)][j & 3], 0.f));
                tb[j] = f2bf(fmaxf(cB[2 * ks + (j >> 2)][j & 3], 0.f));
            }
            qA[ks] = ta; qB[ks] = tb;
        }

        v4f VA = (v4f){0, 0, 0, 0}, VB = (v4f){0, 0, 0, 0};
#pragma unroll
        for (int ks = 0; ks < 2; ks++) {
            v8s wk = WFRAG(108 + ks);
            VA = MFMA(wk, qA[ks], VA, 0, 0, 0);
            VB = MFMA(wk, qB[ks], VB, 0, 0, 0);
        }

        if (quad == 0) {
            float cb3v = cb3[0];
            if (tk0 >= 0) out[(size_t)tk0 * 17 + 16] = VA[0] + cb3v;
            if (tk1 >= 0) out[(size_t)tk1 * 17 + 16] = VB[0] + cb3v;
        }
    }
#undef LFRAG
#undef WFRAG
}

// ---------------------------------------------------------------------------

extern "C" void kernel_launch(void* const* d_in, const int* in_sizes, int n_in,
                              void* d_out, int out_size, void* d_ws, size_t ws_size,
                              hipStream_t stream) {
    const float* obs = (const float*)d_in[0];
    const int*  hete = (const int*)d_in[1];
    const float* gp  = (const float*)d_in[2];
    const float* W1  = (const float*)d_in[3];
    const float* b1  = (const float*)d_in[4];
    const float* W2  = (const float*)d_in[5];
    const float* b2  = (const float*)d_in[6];
    const float* W3  = (const float*)d_in[7];
    const float* b3  = (const float*)d_in[8];
    const float* cW1 = (const float*)d_in[9];
    const float* cb1 = (const float*)d_in[10];
    const float* cW2 = (const float*)d_in[11];
    const float* cb2 = (const float*)d_in[12];
    const float* cW3 = (const float*)d_in[13];
    const float* cb3 = (const float*)d_in[14];
    float* out = (float*)d_out;

    // ws layout (stream-order lifetime aliasing, keeps footprint ~1.18 MB):
    //   hdr[32] | bucket[262656] | cnt[1024] | bb[1024]
    //   wp (133120 B) ALIASES cnt onward — cnt dead after prefix, bb dead
    //   after scatter, prep (which writes wp) runs after scatter.
    int*   hdr    = (int*)d_ws;
    int*   bucket = hdr + 32;                  // 262656 ints
    int*   cnt    = bucket + 262656;           // 1024 ints (dead after prefix)
    int*   bb     = cnt + 1024;                // 1024 ints (dead after scatter)
    short* wp     = (short*)cnt;               // 130*512 shorts = 133120 B

    count_kernel  <<<256, 256, 0, stream>>>(hete, cnt);
    prefix_kernel <<<1,   256, 0, stream>>>(cnt, hdr, bb, bucket);
    scatter_kernel<<<256, 256, 0, stream>>>(hete, bb, bucket);
    prep_kernel   <<<130,  64, 0, stream>>>(W1, cW1, W2, cW2, W3, cW3,
                                            b1, cb1, b2, cb2, wp);
    main_kernel   <<<2051, 256, 0, stream>>>(obs, gp, bucket, hdr, wp,
                                             b3, cb3, out);
}